// Round 5
// baseline (934.733 us; speedup 1.0000x reference)
//
#include <hip/hip_runtime.h>

#define N_TOTAL 60000
#define N_X     50000
#define N_EDGE  1920000
#define NFEAT   512
#define NHID    256
#define SLOTS   96      // fixed per-row edge capacity; Poisson(32) max over 60000 rows ~ 60
#define NCHUNK  8       // feature chunks of 32 feats (64 B bf16); chunk c -> XCD c via bid%8

typedef __attribute__((ext_vector_type(8))) short bf16x8;
typedef __attribute__((ext_vector_type(4))) float f32x4;
typedef __attribute__((ext_vector_type(4))) unsigned u32x4;

__device__ __forceinline__ unsigned short f2bf(float f) {
    unsigned u = __float_as_uint(f);
    unsigned r = (u + 0x7FFFu + ((u >> 16) & 1u)) >> 16;   // RNE
    return (unsigned short)r;
}
__device__ __forceinline__ float bf_lo(unsigned u) { return __uint_as_float(u << 16); }
__device__ __forceinline__ float bf_hi(unsigned u) { return __uint_as_float(u & 0xFFFF0000u); }

// ---------------- all W[K][256] fp32 -> WT[256][K] bf16 in one kernel ----------------
__global__ __launch_bounds__(256)
void cvt_w_all_kernel(const float* __restrict__ w1, const float* __restrict__ w2,
                      const float* __restrict__ w3, short* __restrict__ w1T,
                      short* __restrict__ w2T, short* __restrict__ w3T)
{
    int n = blockIdx.x;
    for (int k = threadIdx.x; k < NFEAT; k += 256)
        w1T[(size_t)n * NFEAT + k] = (short)f2bf(w1[(size_t)k * NHID + n]);
    for (int k = threadIdx.x; k < NHID; k += 256)
        w2T[(size_t)n * NHID + k] = (short)f2bf(w2[(size_t)k * NHID + n]);
    for (int k = threadIdx.x; k < NHID; k += 256)
        w3T[(size_t)n * NHID + k] = (short)f2bf(w3[(size_t)k * NHID + n]);
}

// ---------------- bf16 MFMA GEMM: C = A[M x K] @ BT[256 x K]^T ----------------
// C is written in feature-chunked layout: C[(col>>5)][row][col&31], chunk stride M*32.
#define LDA 40   // padded LDS row stride (shorts): 80B -> 2-way bank alias only (free)

template<bool AF32>
__global__ __launch_bounds__(256)
void gemm_bt_kernel(const float* __restrict__ Af, const float* __restrict__ A2f, int split,
                    const short* __restrict__ Ab, const short* __restrict__ BT,
                    short* __restrict__ C, int M, int K)
{
    __shared__ short As[128 * LDA];
    __shared__ short Bs[128 * LDA];
    const int t    = threadIdx.x;
    const int lane = t & 63;
    const int wave = t >> 6;
    const int wm   = wave & 1;
    const int wn   = wave >> 1;
    const int l16  = lane & 15;
    const int quad = lane >> 4;
    const int bm   = blockIdx.x * 128;
    const int bn   = blockIdx.y * 128;

    f32x4 acc[4][4] = {};

    const int srow = t >> 2;
    const int sch  = t & 3;
    const int frow = t >> 1;
    const int fh   = t & 1;

    for (int kk = 0; kk < K; kk += 32) {
        if (AF32) {
            int row = bm + frow;
            float4 v0 = {}, v1 = {}, v2 = {}, v3 = {};
            if (row < M) {
                const float* src = (row < split) ? (Af + (size_t)row * K)
                                                 : (A2f + (size_t)(row - split) * K);
                const float4* p = (const float4*)(src + kk + fh * 16);
                v0 = p[0]; v1 = p[1]; v2 = p[2]; v3 = p[3];
            }
            short* dst = &As[frow * LDA + fh * 16];
            short tmp[16] = {
                (short)f2bf(v0.x), (short)f2bf(v0.y), (short)f2bf(v0.z), (short)f2bf(v0.w),
                (short)f2bf(v1.x), (short)f2bf(v1.y), (short)f2bf(v1.z), (short)f2bf(v1.w),
                (short)f2bf(v2.x), (short)f2bf(v2.y), (short)f2bf(v2.z), (short)f2bf(v2.w),
                (short)f2bf(v3.x), (short)f2bf(v3.y), (short)f2bf(v3.z), (short)f2bf(v3.w)};
            *(bf16x8*)(dst)     = *(const bf16x8*)&tmp[0];
            *(bf16x8*)(dst + 8) = *(const bf16x8*)&tmp[8];
        } else {
            bf16x8 va0 = {}, va1 = {};
            int r0 = bm + srow, r1 = bm + srow + 64;
            if (r0 < M) va0 = *(const bf16x8*)(Ab + (size_t)r0 * K + kk + sch * 8);
            if (r1 < M) va1 = *(const bf16x8*)(Ab + (size_t)r1 * K + kk + sch * 8);
            *(bf16x8*)&As[srow * LDA + sch * 8]        = va0;
            *(bf16x8*)&As[(srow + 64) * LDA + sch * 8] = va1;
        }
        {
            bf16x8 vb0 = *(const bf16x8*)(BT + (size_t)(bn + srow) * K + kk + sch * 8);
            bf16x8 vb1 = *(const bf16x8*)(BT + (size_t)(bn + srow + 64) * K + kk + sch * 8);
            *(bf16x8*)&Bs[srow * LDA + sch * 8]        = vb0;
            *(bf16x8*)&Bs[(srow + 64) * LDA + sch * 8] = vb1;
        }
        __syncthreads();

        bf16x8 af[4], bfr[4];
        #pragma unroll
        for (int i = 0; i < 4; i++) {
            af[i]  = *(const bf16x8*)&As[(wm * 64 + i * 16 + l16) * LDA + quad * 8];
            bfr[i] = *(const bf16x8*)&Bs[(wn * 64 + i * 16 + l16) * LDA + quad * 8];
        }
        #pragma unroll
        for (int i = 0; i < 4; i++)
            #pragma unroll
            for (int j = 0; j < 4; j++)
                acc[i][j] = __builtin_amdgcn_mfma_f32_16x16x32_bf16(af[i], bfr[j], acc[i][j], 0, 0, 0);
        __syncthreads();
    }

    #pragma unroll
    for (int i = 0; i < 4; i++) {
        #pragma unroll
        for (int r = 0; r < 4; r++) {
            int row = bm + wm * 64 + i * 16 + quad * 4 + r;
            if (row < M) {
                #pragma unroll
                for (int j = 0; j < 4; j++) {
                    int col = bn + wn * 64 + j * 16 + l16;
                    size_t idx = (size_t)(col >> 5) * M * 32 + (size_t)row * 32 + (col & 31);
                    __builtin_nontemporal_store((short)f2bf(acc[i][j][r]), C + idx);
                }
            }
        }
    }
}

// ---------------- direct-slot CSR build ----------------
__global__ __launch_bounds__(256)
void init_cursor_kernel(int* __restrict__ cursor)
{
    int i = blockIdx.x * 256 + threadIdx.x;
    if (i < N_TOTAL) cursor[i] = i * SLOTS;
}

// Range-filtered edge scatter into fixed per-row slots: block b handles edge-chunk b>>3,
// row range (b&7)*7500..+7500. Writes for one span stay on one XCD -> L2 write combining.
__global__ __launch_bounds__(256)
void scatter_edges_kernel(const int* __restrict__ rows, const int* __restrict__ cols,
                          const float* __restrict__ vals, int* __restrict__ cursor,
                          unsigned* __restrict__ edges)
{
    const int b = blockIdx.x;
    const int g = b & 7;
    const int i = (b >> 3) * 256 + threadIdx.x;
    const int lo = g * (N_TOTAL / 8);
    const int hi = lo + (N_TOTAL / 8);
    int r = __builtin_nontemporal_load(&rows[i]);
    if (r >= lo && r < hi) {
        unsigned rec = (unsigned)cols[i] | ((unsigned)f2bf(vals[i]) << 16);
        int p = atomicAdd(&cursor[r], 1);
        edges[p] = rec;
    }
}

// ---------------- SpMM + bias + ReLU, chunked + sequential per-group accumulation -------
// Block = (row-group, chunk); chunk = bid & 7 -> XCD affinity, so XCD c only gathers from
// supportC[c] = 3.84 MB < 4 MiB L2 (R3: cut FETCH 423->66 MB). Wave = 16 groups x 4
// lanes; each group owns one (row, chunk), walks its edge list sequentially, accumulates
// 8 f32/lane in registers (R4: no shfl tree / LDS / lgkm waits). R5 fixes R4's 430 MB of
// junk gather traffic: (1) edges buffer is zeroed before scatter, so padded slots are
// (col=0, w=0) records -> zero contribution, always-hot line; (2) loop bound is
// PER-GROUP (divergent, exec-masked) instead of __any over the wave, so finished groups
// issue nothing; (3) edge-granule loads are nontemporal, keeping the 23 MB/XCD edge
// stream from evicting the resident support chunk (L1 still serves the 4-granule reuse
// of each 64-B edge line). No barriers anywhere.
// MODE 0: write packed bf16 h. MODE 1: fp32 scatter via pos.
template<int MODE>
__global__ __launch_bounds__(256)
void spmm_relu_kernel(const int* __restrict__ row_end, const unsigned* __restrict__ edges,
                      const u32x4* __restrict__ supportC, const float* __restrict__ bias,
                      u32x4* __restrict__ out_bf, float* __restrict__ out_f32,
                      const int* __restrict__ pos, int nrows)
{
    const int chunk = blockIdx.x & 7;
    const int grp   = blockIdx.x >> 3;
    const int wave  = threadIdx.x >> 6;
    const int lane  = threadIdx.x & 63;
    const int gid   = lane >> 2;       // 16 row-groups per wave
    const int fl    = lane & 3;        // u32x4 index within 64-B chunk-row
    const int rbase = grp * 64 + wave * 16;
    if (rbase >= nrows) return;        // wave-uniform exit; kernel has no barriers
    const int r  = rbase + gid;
    const int rc = min(r, nrows - 1);
    const int start = rc * SLOTS;
    const int len   = row_end[rc] - start;          // 4-lane broadcast load
    // chunk slice: [N_TOTAL][4] u32x4 (64 B per row)
    const u32x4* __restrict__ sb = supportC + (size_t)chunk * N_TOTAL * 4 + fl;
    const u32x4* __restrict__ ep = (const u32x4*)(edges + start);   // 16-B aligned

    float a[8] = {};
    for (int it = 0; it < len; it += 4) {           // per-group bound; exec-masked
        u32x4 e = __builtin_nontemporal_load(&ep[it >> 2]);  // 4 records, 4-lane bcast
        #pragma unroll
        for (int s = 0; s < 4; s++) {
            unsigned es = e[s];                     // padded slot: zeroed -> col 0, w 0
            u32x4 u = sb[(size_t)(es & 0xFFFFu) * 4];
            float w = bf_hi(es);
            #pragma unroll
            for (int k = 0; k < 4; k++) {
                a[2*k]     += w * bf_lo(u[k]);
                a[2*k + 1] += w * bf_hi(u[k]);
            }
        }
    }

    const f32x4* bb = (const f32x4*)bias + chunk * 8 + fl * 2;
    f32x4 bv0 = bb[0], bv1 = bb[1];
    float o[8];
    #pragma unroll
    for (int k = 0; k < 8; k++) {
        float bk = (k < 4) ? bv0[k] : bv1[k - 4];
        o[k] = fmaxf(a[k] + bk, 0.f);
    }
    if (r < nrows) {
        if (MODE == 1) {
            f32x4 q0 = {o[0], o[1], o[2], o[3]};
            f32x4 q1 = {o[4], o[5], o[6], o[7]};
            f32x4* dst = (f32x4*)out_f32 + (size_t)pos[r] * 64 + chunk * 8 + fl * 2;
            __builtin_nontemporal_store(q0, dst);
            __builtin_nontemporal_store(q1, dst + 1);
        } else {
            u32x4 q;
            #pragma unroll
            for (int k = 0; k < 4; k++)
                q[k] = (unsigned)f2bf(o[2*k]) | ((unsigned)f2bf(o[2*k + 1]) << 16);
            __builtin_nontemporal_store(q, out_bf + (size_t)r * 32 + chunk * 4 + fl);
        }
    }
}

extern "C" void kernel_launch(void* const* d_in, const int* in_sizes, int n_in,
                              void* d_out, int out_size, void* d_ws, size_t ws_size,
                              hipStream_t stream)
{
    const float* x     = (const float*)d_in[0];
    const float* motif = (const float*)d_in[1];
    const int*   rows  = (const int*)d_in[2];
    const int*   cols  = (const int*)d_in[3];
    const float* vals  = (const float*)d_in[4];
    const int*   pos   = (const int*)d_in[5];
    const float* w1 = (const float*)d_in[7];
    const float* b1 = (const float*)d_in[8];
    const float* w2 = (const float*)d_in[9];
    const float* b2 = (const float*)d_in[10];
    const float* w3 = (const float*)d_in[11];
    const float* b3 = (const float*)d_in[12];
    (void)ws_size; (void)n_in; (void)in_sizes;

    char* ws = (char*)d_ws;
    size_t off = 0;
    short* h_bf     = (short*)(ws + off); off += (size_t)N_TOTAL * NHID * 2;      // 30.72 MB
    short* support  = (short*)(ws + off); off += (size_t)N_TOTAL * NHID * 2;      // 30.72 MB (chunked)
    short* w1T      = (short*)(ws + off); off += (size_t)NHID * NFEAT * 2;
    short* w2T      = (short*)(ws + off); off += (size_t)NHID * NHID * 2;
    short* w3T      = (short*)(ws + off); off += (size_t)NHID * NHID * 2;
    int* cursor     = (int*)(ws + off);   off += 60032 * 4;
    unsigned* edges = (unsigned*)(ws + off); off += (size_t)N_TOTAL * SLOTS * 4;  // 23.04 MB

    // --- independent prep first ---
    hipMemsetAsync(d_out, 0, (size_t)out_size * sizeof(float), stream);
    hipMemsetAsync(edges, 0, (size_t)N_TOTAL * SLOTS * 4, stream);   // padded slots -> (col 0, w 0)
    cvt_w_all_kernel<<<NHID, 256, 0, stream>>>(w1, w2, w3, w1T, w2T, w3T);
    init_cursor_kernel<<<(N_TOTAL + 255) / 256, 256, 0, stream>>>(cursor);
    scatter_edges_kernel<<<(N_EDGE / 256) * 8, 256, 0, stream>>>(rows, cols, vals, cursor, edges);

    dim3 ggrid((N_TOTAL + 127) / 128, NHID / 128);
    const int sgrid0 = ((N_TOTAL + 63) / 64) * NCHUNK;
    const int sgrid1 = ((N_X + 63) / 64) * NCHUNK;

    // layer 1 (fp32 A converted during staging)
    gemm_bt_kernel<true><<<ggrid, 256, 0, stream>>>(x, motif, N_X, nullptr, w1T, support, N_TOTAL, NFEAT);
    spmm_relu_kernel<0><<<sgrid0, 256, 0, stream>>>(cursor, edges, (const u32x4*)support, b1,
                                                    (u32x4*)h_bf, nullptr, nullptr, N_TOTAL);
    // layer 2
    gemm_bt_kernel<false><<<ggrid, 256, 0, stream>>>(nullptr, nullptr, 0, h_bf, w2T, support, N_TOTAL, NHID);
    spmm_relu_kernel<0><<<sgrid0, 256, 0, stream>>>(cursor, edges, (const u32x4*)support, b2,
                                                    (u32x4*)h_bf, nullptr, nullptr, N_TOTAL);
    // layer 3: only rows < N_X needed; fp32 scatter straight into d_out
    gemm_bt_kernel<false><<<ggrid, 256, 0, stream>>>(nullptr, nullptr, 0, h_bf, w3T, support, N_TOTAL, NHID);
    spmm_relu_kernel<1><<<sgrid1, 256, 0, stream>>>(cursor, edges, (const u32x4*)support, b3,
                                                    nullptr, (float*)d_out, pos, N_X);
}

// Round 6
// 702.377 us; speedup vs baseline: 1.3308x; 1.3308x over previous
//
#include <hip/hip_runtime.h>

#define N_TOTAL 60000
#define N_X     50000
#define N_EDGE  1920000
#define NFEAT   512
#define NHID    256
#define SLOTS   96      // fixed per-row edge capacity; Poisson(32) max over 60000 rows ~ 60
#define NCHUNK  8       // feature chunks of 32 feats (64 B bf16); chunk c -> XCD c via bid%8

typedef __attribute__((ext_vector_type(8))) short bf16x8;
typedef __attribute__((ext_vector_type(4))) float f32x4;
typedef __attribute__((ext_vector_type(4))) unsigned u32x4;

__device__ __forceinline__ unsigned short f2bf(float f) {
    unsigned u = __float_as_uint(f);
    unsigned r = (u + 0x7FFFu + ((u >> 16) & 1u)) >> 16;   // RNE
    return (unsigned short)r;
}
__device__ __forceinline__ float bf_lo(unsigned u) { return __uint_as_float(u << 16); }
__device__ __forceinline__ float bf_hi(unsigned u) { return __uint_as_float(u & 0xFFFF0000u); }

// ---------------- all W[K][256] fp32 -> WT[256][K] bf16 in one kernel ----------------
__global__ __launch_bounds__(256)
void cvt_w_all_kernel(const float* __restrict__ w1, const float* __restrict__ w2,
                      const float* __restrict__ w3, short* __restrict__ w1T,
                      short* __restrict__ w2T, short* __restrict__ w3T)
{
    int n = blockIdx.x;
    for (int k = threadIdx.x; k < NFEAT; k += 256)
        w1T[(size_t)n * NFEAT + k] = (short)f2bf(w1[(size_t)k * NHID + n]);
    for (int k = threadIdx.x; k < NHID; k += 256)
        w2T[(size_t)n * NHID + k] = (short)f2bf(w2[(size_t)k * NHID + n]);
    for (int k = threadIdx.x; k < NHID; k += 256)
        w3T[(size_t)n * NHID + k] = (short)f2bf(w3[(size_t)k * NHID + n]);
}

// ---------------- bf16 MFMA GEMM: C = A[M x K] @ BT[256 x K]^T ----------------
// C is written in feature-chunked layout: C[(col>>5)][row][col&31], chunk stride M*32.
#define LDA 40   // padded LDS row stride (shorts): 80B -> 2-way bank alias only (free)

template<bool AF32>
__global__ __launch_bounds__(256)
void gemm_bt_kernel(const float* __restrict__ Af, const float* __restrict__ A2f, int split,
                    const short* __restrict__ Ab, const short* __restrict__ BT,
                    short* __restrict__ C, int M, int K)
{
    __shared__ short As[128 * LDA];
    __shared__ short Bs[128 * LDA];
    const int t    = threadIdx.x;
    const int lane = t & 63;
    const int wave = t >> 6;
    const int wm   = wave & 1;
    const int wn   = wave >> 1;
    const int l16  = lane & 15;
    const int quad = lane >> 4;
    const int bm   = blockIdx.x * 128;
    const int bn   = blockIdx.y * 128;

    f32x4 acc[4][4] = {};

    const int srow = t >> 2;
    const int sch  = t & 3;
    const int frow = t >> 1;
    const int fh   = t & 1;

    for (int kk = 0; kk < K; kk += 32) {
        if (AF32) {
            int row = bm + frow;
            float4 v0 = {}, v1 = {}, v2 = {}, v3 = {};
            if (row < M) {
                const float* src = (row < split) ? (Af + (size_t)row * K)
                                                 : (A2f + (size_t)(row - split) * K);
                const float4* p = (const float4*)(src + kk + fh * 16);
                v0 = p[0]; v1 = p[1]; v2 = p[2]; v3 = p[3];
            }
            short* dst = &As[frow * LDA + fh * 16];
            short tmp[16] = {
                (short)f2bf(v0.x), (short)f2bf(v0.y), (short)f2bf(v0.z), (short)f2bf(v0.w),
                (short)f2bf(v1.x), (short)f2bf(v1.y), (short)f2bf(v1.z), (short)f2bf(v1.w),
                (short)f2bf(v2.x), (short)f2bf(v2.y), (short)f2bf(v2.z), (short)f2bf(v2.w),
                (short)f2bf(v3.x), (short)f2bf(v3.y), (short)f2bf(v3.z), (short)f2bf(v3.w)};
            *(bf16x8*)(dst)     = *(const bf16x8*)&tmp[0];
            *(bf16x8*)(dst + 8) = *(const bf16x8*)&tmp[8];
        } else {
            bf16x8 va0 = {}, va1 = {};
            int r0 = bm + srow, r1 = bm + srow + 64;
            if (r0 < M) va0 = *(const bf16x8*)(Ab + (size_t)r0 * K + kk + sch * 8);
            if (r1 < M) va1 = *(const bf16x8*)(Ab + (size_t)r1 * K + kk + sch * 8);
            *(bf16x8*)&As[srow * LDA + sch * 8]        = va0;
            *(bf16x8*)&As[(srow + 64) * LDA + sch * 8] = va1;
        }
        {
            bf16x8 vb0 = *(const bf16x8*)(BT + (size_t)(bn + srow) * K + kk + sch * 8);
            bf16x8 vb1 = *(const bf16x8*)(BT + (size_t)(bn + srow + 64) * K + kk + sch * 8);
            *(bf16x8*)&Bs[srow * LDA + sch * 8]        = vb0;
            *(bf16x8*)&Bs[(srow + 64) * LDA + sch * 8] = vb1;
        }
        __syncthreads();

        bf16x8 af[4], bfr[4];
        #pragma unroll
        for (int i = 0; i < 4; i++) {
            af[i]  = *(const bf16x8*)&As[(wm * 64 + i * 16 + l16) * LDA + quad * 8];
            bfr[i] = *(const bf16x8*)&Bs[(wn * 64 + i * 16 + l16) * LDA + quad * 8];
        }
        #pragma unroll
        for (int i = 0; i < 4; i++)
            #pragma unroll
            for (int j = 0; j < 4; j++)
                acc[i][j] = __builtin_amdgcn_mfma_f32_16x16x32_bf16(af[i], bfr[j], acc[i][j], 0, 0, 0);
        __syncthreads();
    }

    #pragma unroll
    for (int i = 0; i < 4; i++) {
        #pragma unroll
        for (int r = 0; r < 4; r++) {
            int row = bm + wm * 64 + i * 16 + quad * 4 + r;
            if (row < M) {
                #pragma unroll
                for (int j = 0; j < 4; j++) {
                    int col = bn + wn * 64 + j * 16 + l16;
                    size_t idx = (size_t)(col >> 5) * M * 32 + (size_t)row * 32 + (col & 31);
                    __builtin_nontemporal_store((short)f2bf(acc[i][j][r]), C + idx);
                }
            }
        }
    }
}

// ---------------- direct-slot CSR build ----------------
__global__ __launch_bounds__(256)
void init_cursor_kernel(int* __restrict__ cursor)
{
    int i = blockIdx.x * 256 + threadIdx.x;
    if (i < N_TOTAL) cursor[i] = i * SLOTS;
}

// Range-filtered edge scatter into fixed per-row slots: block b handles edge-chunk b>>3,
// row range (b&7)*7500..+7500. Writes for one span stay on one XCD -> L2 write combining.
__global__ __launch_bounds__(256)
void scatter_edges_kernel(const int* __restrict__ rows, const int* __restrict__ cols,
                          const float* __restrict__ vals, int* __restrict__ cursor,
                          unsigned* __restrict__ edges)
{
    const int b = blockIdx.x;
    const int g = b & 7;
    const int i = (b >> 3) * 256 + threadIdx.x;
    const int lo = g * (N_TOTAL / 8);
    const int hi = lo + (N_TOTAL / 8);
    int r = __builtin_nontemporal_load(&rows[i]);
    if (r >= lo && r < hi) {
        unsigned rec = (unsigned)cols[i] | ((unsigned)f2bf(vals[i]) << 16);
        int p = atomicAdd(&cursor[r], 1);
        edges[p] = rec;
    }
}

// ---------------- SpMM + bias + ReLU, chunked + prefetched sequential accumulation -----
// Block = (row-group, chunk); chunk = bid & 7 -> XCD affinity, so XCD c only gathers from
// supportC[c] = 3.84 MB < 4 MiB L2 (R3: cut FETCH 423->66 MB). Wave = 16 groups x 4
// lanes; each group owns one (row, chunk), walks its edge list sequentially, accumulates
// 8 f32/lane in registers. Edges are PLAIN loads (R5's nontemporal hint pushed the 8x
// cross-XCD edge re-reads past L3 to HBM — +184 MB FETCH — and put HBM latency on the
// address-producing load of every gather chain: 150->194 us regression. L3 serves them
// at ~200-400 cy when cached normally). R6: 2-granule unroll with 1-iteration-ahead
// prefetch (e0,e1 consumed while n0,n1 load) -> edge latency hidden under 8 gathers +
// ~128 VALU; 8 independent gathers in flight per group. Padded slots are zeroed
// (col 0 = hot broadcast line, w = 0); prefetch may over-read <=48 B past the last
// row's slots -> edges allocation carries a 256 B pad; over-read values are discarded.
// No barriers anywhere.
// MODE 0: write packed bf16 h. MODE 1: fp32 scatter via pos.
template<int MODE>
__global__ __launch_bounds__(256)
void spmm_relu_kernel(const int* __restrict__ row_end, const unsigned* __restrict__ edges,
                      const u32x4* __restrict__ supportC, const float* __restrict__ bias,
                      u32x4* __restrict__ out_bf, float* __restrict__ out_f32,
                      const int* __restrict__ pos, int nrows)
{
    const int chunk = blockIdx.x & 7;
    const int grp   = blockIdx.x >> 3;
    const int wave  = threadIdx.x >> 6;
    const int lane  = threadIdx.x & 63;
    const int gid   = lane >> 2;       // 16 row-groups per wave
    const int fl    = lane & 3;        // u32x4 index within 64-B chunk-row
    const int rbase = grp * 64 + wave * 16;
    if (rbase >= nrows) return;        // wave-uniform exit; kernel has no barriers
    const int r  = rbase + gid;
    const int rc = min(r, nrows - 1);
    const int start = rc * SLOTS;
    const int len   = row_end[rc] - start;          // 4-lane broadcast load
    // chunk slice: [N_TOTAL][4] u32x4 (64 B per row)
    const u32x4* __restrict__ sb = supportC + (size_t)chunk * N_TOTAL * 4 + fl;
    const u32x4* __restrict__ ep = (const u32x4*)(edges + start);   // 16-B aligned

    float a[8] = {};
    u32x4 e0 = ep[0];                  // slots 0..3 (zeroed pads if len small)
    u32x4 e1 = ep[1];                  // slots 4..7
    for (int it = 0; it < len; it += 8) {           // per-group bound; exec-masked
        const int g = it >> 2;
        u32x4 n0 = ep[g + 2];          // prefetch next iteration's granules
        u32x4 n1 = ep[g + 3];          // (may over-read into 256 B pad; value discarded)
        #pragma unroll
        for (int s = 0; s < 4; s++) {
            unsigned es = e0[s];       // padded slot: zeroed -> col 0, w 0
            u32x4 u = sb[(size_t)(es & 0xFFFFu) * 4];
            float w = bf_hi(es);
            #pragma unroll
            for (int k = 0; k < 4; k++) {
                a[2*k]     += w * bf_lo(u[k]);
                a[2*k + 1] += w * bf_hi(u[k]);
            }
        }
        #pragma unroll
        for (int s = 0; s < 4; s++) {
            unsigned es = e1[s];
            u32x4 u = sb[(size_t)(es & 0xFFFFu) * 4];
            float w = bf_hi(es);
            #pragma unroll
            for (int k = 0; k < 4; k++) {
                a[2*k]     += w * bf_lo(u[k]);
                a[2*k + 1] += w * bf_hi(u[k]);
            }
        }
        e0 = n0; e1 = n1;
    }

    const f32x4* bb = (const f32x4*)bias + chunk * 8 + fl * 2;
    f32x4 bv0 = bb[0], bv1 = bb[1];
    float o[8];
    #pragma unroll
    for (int k = 0; k < 8; k++) {
        float bk = (k < 4) ? bv0[k] : bv1[k - 4];
        o[k] = fmaxf(a[k] + bk, 0.f);
    }
    if (r < nrows) {
        if (MODE == 1) {
            f32x4 q0 = {o[0], o[1], o[2], o[3]};
            f32x4 q1 = {o[4], o[5], o[6], o[7]};
            f32x4* dst = (f32x4*)out_f32 + (size_t)pos[r] * 64 + chunk * 8 + fl * 2;
            __builtin_nontemporal_store(q0, dst);
            __builtin_nontemporal_store(q1, dst + 1);
        } else {
            u32x4 q;
            #pragma unroll
            for (int k = 0; k < 4; k++)
                q[k] = (unsigned)f2bf(o[2*k]) | ((unsigned)f2bf(o[2*k + 1]) << 16);
            __builtin_nontemporal_store(q, out_bf + (size_t)r * 32 + chunk * 4 + fl);
        }
    }
}

extern "C" void kernel_launch(void* const* d_in, const int* in_sizes, int n_in,
                              void* d_out, int out_size, void* d_ws, size_t ws_size,
                              hipStream_t stream)
{
    const float* x     = (const float*)d_in[0];
    const float* motif = (const float*)d_in[1];
    const int*   rows  = (const int*)d_in[2];
    const int*   cols  = (const int*)d_in[3];
    const float* vals  = (const float*)d_in[4];
    const int*   pos   = (const int*)d_in[5];
    const float* w1 = (const float*)d_in[7];
    const float* b1 = (const float*)d_in[8];
    const float* w2 = (const float*)d_in[9];
    const float* b2 = (const float*)d_in[10];
    const float* w3 = (const float*)d_in[11];
    const float* b3 = (const float*)d_in[12];
    (void)ws_size; (void)n_in; (void)in_sizes;

    char* ws = (char*)d_ws;
    size_t off = 0;
    short* h_bf     = (short*)(ws + off); off += (size_t)N_TOTAL * NHID * 2;      // 30.72 MB
    short* support  = (short*)(ws + off); off += (size_t)N_TOTAL * NHID * 2;      // 30.72 MB (chunked)
    short* w1T      = (short*)(ws + off); off += (size_t)NHID * NFEAT * 2;
    short* w2T      = (short*)(ws + off); off += (size_t)NHID * NHID * 2;
    short* w3T      = (short*)(ws + off); off += (size_t)NHID * NHID * 2;
    int* cursor     = (int*)(ws + off);   off += 60032 * 4;
    unsigned* edges = (unsigned*)(ws + off); off += (size_t)N_TOTAL * SLOTS * 4 + 256;  // 23.04 MB + prefetch pad

    // --- independent prep first ---
    hipMemsetAsync(d_out, 0, (size_t)out_size * sizeof(float), stream);
    hipMemsetAsync(edges, 0, (size_t)N_TOTAL * SLOTS * 4, stream);   // padded slots -> (col 0, w 0)
    cvt_w_all_kernel<<<NHID, 256, 0, stream>>>(w1, w2, w3, w1T, w2T, w3T);
    init_cursor_kernel<<<(N_TOTAL + 255) / 256, 256, 0, stream>>>(cursor);
    scatter_edges_kernel<<<(N_EDGE / 256) * 8, 256, 0, stream>>>(rows, cols, vals, cursor, edges);

    dim3 ggrid((N_TOTAL + 127) / 128, NHID / 128);
    const int sgrid0 = ((N_TOTAL + 63) / 64) * NCHUNK;
    const int sgrid1 = ((N_X + 63) / 64) * NCHUNK;

    // layer 1 (fp32 A converted during staging)
    gemm_bt_kernel<true><<<ggrid, 256, 0, stream>>>(x, motif, N_X, nullptr, w1T, support, N_TOTAL, NFEAT);
    spmm_relu_kernel<0><<<sgrid0, 256, 0, stream>>>(cursor, edges, (const u32x4*)support, b1,
                                                    (u32x4*)h_bf, nullptr, nullptr, N_TOTAL);
    // layer 2
    gemm_bt_kernel<false><<<ggrid, 256, 0, stream>>>(nullptr, nullptr, 0, h_bf, w2T, support, N_TOTAL, NHID);
    spmm_relu_kernel<0><<<sgrid0, 256, 0, stream>>>(cursor, edges, (const u32x4*)support, b2,
                                                    (u32x4*)h_bf, nullptr, nullptr, N_TOTAL);
    // layer 3: only rows < N_X needed; fp32 scatter straight into d_out
    gemm_bt_kernel<false><<<ggrid, 256, 0, stream>>>(nullptr, nullptr, 0, h_bf, w3T, support, N_TOTAL, NHID);
    spmm_relu_kernel<1><<<sgrid1, 256, 0, stream>>>(cursor, edges, (const u32x4*)support, b3,
                                                    nullptr, (float*)d_out, pos, N_X);
}